// Round 1
// baseline (4433.014 us; speedup 1.0000x reference)
//
#include <hip/hip_runtime.h>

// Problem constants
#define BB   16
#define TS   16
#define NNP  4096
#define HID  64
#define KCH  65      // in channels = FC(1) + HID(64)
#define KTOT 195     // KCH * 3 taps
#define OC   256     // 4 gates * HID

// ---------------------------------------------------------------------------
// Pack conv_w (OIHW, 256x65x3x3) -> wp[gate][k][hc], k = ic*3+kh, using kw=1
// (the W dim is size 1 with pad 1, so only the middle kw column matters).
// ---------------------------------------------------------------------------
__global__ void pack_w_kernel(const float* __restrict__ conv_w,
                              float* __restrict__ wp) {
    int idx = blockIdx.x * 256 + threadIdx.x;     // 4*195*64 = 49920 total
    if (idx >= 4 * KTOT * HID) return;
    int hc = idx & 63;
    int k  = (idx >> 6) % KTOT;
    int g  = idx / (KTOT * HID);
    int ic = k / 3, kh = k % 3;
    int oc = g * HID + hc;
    wp[idx] = conv_w[((oc * KCH + ic) * 3 + kh) * 3 + 1];
}

__device__ __forceinline__ float sigmoid_f(float x) {
    return 1.0f / (1.0f + __expf(-x));
}
__device__ __forceinline__ float tanh_f(float x) {
    // |x| bounded (~<=16 for c, gates ~N(0,1)) -> no overflow concern
    float e = __expf(2.0f * x);
    return 1.0f - 2.0f / (e + 1.0f);
}

// ---------------------------------------------------------------------------
// One LSTM timestep.  h/c layout: [B][NN][64] (channel minor -> coalesced).
// Block: 256 threads, handles one b and 64 consecutive n positions.
//   thread: hc = tid & 63, position group = tid >> 6 (16 positions each).
// LDS tile: [66 rows = n0-1..n0+64][66 cols: col0 = x, col 1+j = h_j] (pad 66)
// ---------------------------------------------------------------------------
__global__ __launch_bounds__(256, 4)
void step_kernel(const float* __restrict__ x,
                 const float* __restrict__ wp,
                 const float* __restrict__ conv_b,
                 const float* __restrict__ h_prev,
                 float* __restrict__ h_next,
                 float* __restrict__ c,
                 int t) {
    __shared__ float lds[66 * 66];

    const int b   = blockIdx.x >> 6;
    const int n0  = (blockIdx.x & 63) * 64;
    const int tid = threadIdx.x;

    // stage x column (channel 0)
    for (int idx = tid; idx < 66; idx += 256) {
        int n = n0 - 1 + idx;
        float v = 0.0f;
        if (n >= 0 && n < NNP) v = x[(b * TS + t) * NNP + n];
        lds[idx * 66 + 0] = v;
    }
    // stage h channels (cols 1..64); zeros at t==0 or halo out-of-range
    for (int idx = tid; idx < 66 * 64; idx += 256) {
        int row = idx >> 6;
        int j   = idx & 63;
        int n   = n0 - 1 + row;
        float v = 0.0f;
        if (t > 0 && n >= 0 && n < NNP) v = h_prev[(b * NNP + n) * HID + j];
        lds[row * 66 + 1 + j] = v;
    }
    __syncthreads();

    const int hc    = tid & 63;
    const int pbase = (tid >> 6) * 16;

    float acc_i[16], acc_f[16], acc_o[16], acc_g[16];
#pragma unroll
    for (int p = 0; p < 16; ++p) {
        acc_i[p] = 0.f; acc_f[p] = 0.f; acc_o[p] = 0.f; acc_g[p] = 0.f;
    }

    const float* wpi = wp + hc;   // lane-coalesced weight reads

    for (int ic = 0; ic < KCH; ++ic) {
        // 18-value window of this channel (reused across the 3 taps)
        float v[18];
#pragma unroll
        for (int r = 0; r < 18; ++r) v[r] = lds[(pbase + r) * 66 + ic];
#pragma unroll
        for (int kh = 0; kh < 3; ++kh) {
            int k = ic * 3 + kh;
            float wi = wpi[(0 * KTOT + k) * HID];
            float wf = wpi[(1 * KTOT + k) * HID];
            float wo = wpi[(2 * KTOT + k) * HID];
            float wg = wpi[(3 * KTOT + k) * HID];
#pragma unroll
            for (int p = 0; p < 16; ++p) {
                float vv = v[p + kh];
                acc_i[p] = fmaf(wi, vv, acc_i[p]);
                acc_f[p] = fmaf(wf, vv, acc_f[p]);
                acc_o[p] = fmaf(wo, vv, acc_o[p]);
                acc_g[p] = fmaf(wg, vv, acc_g[p]);
            }
        }
    }

    const float bi = conv_b[hc];
    const float bf = conv_b[64 + hc];
    const float bo = conv_b[128 + hc];
    const float bg = conv_b[192 + hc];

#pragma unroll
    for (int p = 0; p < 16; ++p) {
        int n = n0 + pbase + p;
        int base = (b * NNP + n) * HID + hc;
        float c_old = (t > 0) ? c[base] : 0.0f;
        float si = sigmoid_f(acc_i[p] + bi);
        float sf = sigmoid_f(acc_f[p] + bf);
        float so = sigmoid_f(acc_o[p] + bo);
        float tg = tanh_f(acc_g[p] + bg);
        float cn = sf * c_old + si * tg;
        float hn = so * tanh_f(cn);
        c[base] = cn;
        h_next[base] = hn;
    }
}

// ---------------------------------------------------------------------------
// fc: out[b,t,n] = sum_hc h[b][n][hc]*fc_w[hc] + fc_b, broadcast over t
// ---------------------------------------------------------------------------
__global__ void fc_kernel(const float* __restrict__ h,
                          const float* __restrict__ fc_w,
                          const float* __restrict__ fc_b,
                          float* __restrict__ out) {
    int idx = blockIdx.x * 256 + threadIdx.x;     // (b*NN + n), 65536 total
    const float4* hp = (const float4*)h + idx * 16;
    const float4* wq = (const float4*)fc_w;
    float s = 0.0f;
#pragma unroll
    for (int q = 0; q < 16; ++q) {
        float4 v = hp[q];
        float4 w = wq[q];
        s += v.x * w.x + v.y * w.y + v.z * w.z + v.w * w.w;
    }
    s += fc_b[0];
    int b = idx >> 12;
    int n = idx & (NNP - 1);
#pragma unroll
    for (int t = 0; t < TS; ++t) out[(b * TS + t) * NNP + n] = s;
}

extern "C" void kernel_launch(void* const* d_in, const int* in_sizes, int n_in,
                              void* d_out, int out_size, void* d_ws, size_t ws_size,
                              hipStream_t stream) {
    const float* x      = (const float*)d_in[0];
    const float* conv_w = (const float*)d_in[1];
    const float* conv_b = (const float*)d_in[2];
    const float* fc_w   = (const float*)d_in[3];
    const float* fc_b   = (const float*)d_in[4];
    float* out = (float*)d_out;

    char* ws = (char*)d_ws;
    const size_t wp_bytes = (size_t)4 * KTOT * HID * sizeof(float);   // ~200 KB
    const size_t hc_bytes = (size_t)BB * NNP * HID * sizeof(float);   // 16.78 MB
    size_t off = (wp_bytes + 255) & ~(size_t)255;

    float* wp  = (float*)ws;
    float* h_a = (float*)(ws + off);
    float* h_b = (float*)(ws + off + hc_bytes);
    float* c   = (float*)(ws + off + 2 * hc_bytes);

    pack_w_kernel<<<(4 * KTOT * HID + 255) / 256, 256, 0, stream>>>(conv_w, wp);

    for (int t = 0; t < TS; ++t) {
        float* h_nxt = (t & 1) ? h_b : h_a;
        const float* h_prv = (t & 1) ? h_a : h_b;
        step_kernel<<<BB * (NNP / 64), 256, 0, stream>>>(
            x, wp, conv_b, h_prv, h_nxt, c, t);
    }
    // t=15 (odd) wrote h_b
    fc_kernel<<<BB * NNP / 256, 256, 0, stream>>>(h_b, fc_w, fc_b, out);
}

// Round 2
// 1721.565 us; speedup vs baseline: 2.5750x; 2.5750x over previous
//
#include <hip/hip_runtime.h>

// Problem constants
#define BB   16
#define TS   16
#define NNP  4096
#define HID  64
#define KCH  65      // in channels = FC(1) + HID(64)
#define KTOT 195     // KCH * 3 taps
#define POS  32      // positions per block
#define ROWS (POS + 2)

// ---------------------------------------------------------------------------
// Pack conv_w (OIHW, 256x65x3x3) -> wp[gate][k][hc], k = ic*3+kh, using kw=1
// (the W spatial dim is size 1 with pad 1, so only kw=1 touches real data).
// ---------------------------------------------------------------------------
__global__ void pack_w_kernel(const float* __restrict__ conv_w,
                              float* __restrict__ wp) {
    int idx = blockIdx.x * 256 + threadIdx.x;     // 4*195*64 = 49920 total
    if (idx >= 4 * KTOT * HID) return;
    int hc = idx & 63;
    int k  = (idx >> 6) % KTOT;
    int g  = idx / (KTOT * HID);
    int ic = k / 3, kh = k % 3;
    int oc = g * HID + hc;
    wp[idx] = conv_w[((oc * KCH + ic) * 3 + kh) * 3 + 1];
}

__device__ __forceinline__ float sigmoid_f(float x) {
    return 1.0f / (1.0f + __expf(-x));
}
__device__ __forceinline__ float tanh_f(float x) {
    float e = __expf(2.0f * x);
    return 1.0f - 2.0f / (e + 1.0f);
}

// ---------------------------------------------------------------------------
// One LSTM timestep.  h/c layout: [B][NN][64] (channel minor -> coalesced).
// Block: 256 threads (4 waves), covers one b and 32 consecutive positions.
//   thread: hc = tid & 63, position group pbase = (tid>>6)*8, 8 positions.
//   32 accumulators (4 gates x 8 pos) per thread -> no spills at <=128 VGPR.
// ---------------------------------------------------------------------------
__global__ __launch_bounds__(256, 2)
void step_kernel(const float* __restrict__ x,
                 const float* __restrict__ wp,
                 const float* __restrict__ conv_b,
                 const float* __restrict__ h_prev,
                 float* __restrict__ h_next,
                 float* __restrict__ c,
                 int t) {
    __shared__ float lds_x[ROWS];
    __shared__ float lds_h[ROWS * HID];

    const int b   = blockIdx.x >> 7;           // 128 tiles per batch
    const int n0  = (blockIdx.x & 127) * POS;
    const int tid = threadIdx.x;

    // stage x column (channel 0): 34 scalars
    if (tid < ROWS) {
        int n = n0 - 1 + tid;
        float v = 0.0f;
        if (n >= 0 && n < NNP) v = x[(b * TS + t) * NNP + n];
        lds_x[tid] = v;
    }
    // stage h channels as float4: 34 rows x 16 float4
    for (int idx = tid; idx < ROWS * 16; idx += 256) {
        int row = idx >> 4;
        int q   = idx & 15;
        int n   = n0 - 1 + row;
        float4 v = make_float4(0.f, 0.f, 0.f, 0.f);
        if (t > 0 && n >= 0 && n < NNP)
            v = ((const float4*)h_prev)[(b * NNP + n) * 16 + q];
        ((float4*)lds_h)[row * 16 + q] = v;
    }
    __syncthreads();

    const int hc    = tid & 63;
    const int pbase = (tid >> 6) * 8;          // 0,8,16,24

    float acc_i[8], acc_f[8], acc_o[8], acc_g[8];
#pragma unroll
    for (int p = 0; p < 8; ++p) {
        acc_i[p] = 0.f; acc_f[p] = 0.f; acc_o[p] = 0.f; acc_g[p] = 0.f;
    }

    const float* wpi = wp + hc;   // lane-coalesced weight reads (L1/L2 hit)

    // ---- channel 0: x ----
    {
        float v[10];
#pragma unroll
        for (int r = 0; r < 10; ++r) v[r] = lds_x[pbase + r];
#pragma unroll
        for (int kh = 0; kh < 3; ++kh) {
            int k = kh;  // ic = 0
            float wi = wpi[(0 * KTOT + k) * HID];
            float wf = wpi[(1 * KTOT + k) * HID];
            float wo = wpi[(2 * KTOT + k) * HID];
            float wg = wpi[(3 * KTOT + k) * HID];
#pragma unroll
            for (int p = 0; p < 8; ++p) {
                float vv = v[p + kh];
                acc_i[p] = fmaf(wi, vv, acc_i[p]);
                acc_f[p] = fmaf(wf, vv, acc_f[p]);
                acc_o[p] = fmaf(wo, vv, acc_o[p]);
                acc_g[p] = fmaf(wg, vv, acc_g[p]);
            }
        }
    }

    // ---- channels 1..64: h_prev ----
    for (int j = 0; j < HID; ++j) {
        float v[10];
#pragma unroll
        for (int r = 0; r < 10; ++r) v[r] = lds_h[(pbase + r) * HID + j];
#pragma unroll
        for (int kh = 0; kh < 3; ++kh) {
            int k = (1 + j) * 3 + kh;
            float wi = wpi[(0 * KTOT + k) * HID];
            float wf = wpi[(1 * KTOT + k) * HID];
            float wo = wpi[(2 * KTOT + k) * HID];
            float wg = wpi[(3 * KTOT + k) * HID];
#pragma unroll
            for (int p = 0; p < 8; ++p) {
                float vv = v[p + kh];
                acc_i[p] = fmaf(wi, vv, acc_i[p]);
                acc_f[p] = fmaf(wf, vv, acc_f[p]);
                acc_o[p] = fmaf(wo, vv, acc_o[p]);
                acc_g[p] = fmaf(wg, vv, acc_g[p]);
            }
        }
    }

    const float bi = conv_b[hc];
    const float bf = conv_b[64 + hc];
    const float bo = conv_b[128 + hc];
    const float bg = conv_b[192 + hc];

#pragma unroll
    for (int p = 0; p < 8; ++p) {
        int n = n0 + pbase + p;
        int base = (b * NNP + n) * HID + hc;
        float c_old = (t > 0) ? c[base] : 0.0f;
        float si = sigmoid_f(acc_i[p] + bi);
        float sf = sigmoid_f(acc_f[p] + bf);
        float so = sigmoid_f(acc_o[p] + bo);
        float tg = tanh_f(acc_g[p] + bg);
        float cn = sf * c_old + si * tg;
        float hn = so * tanh_f(cn);
        c[base] = cn;
        h_next[base] = hn;
    }
}

// ---------------------------------------------------------------------------
// fc: out[b,t,n] = sum_hc h[b][n][hc]*fc_w[hc] + fc_b, broadcast over t
// ---------------------------------------------------------------------------
__global__ void fc_kernel(const float* __restrict__ h,
                          const float* __restrict__ fc_w,
                          const float* __restrict__ fc_b,
                          float* __restrict__ out) {
    int idx = blockIdx.x * 256 + threadIdx.x;     // (b*NN + n), 65536 total
    const float4* hp = (const float4*)h + idx * 16;
    const float4* wq = (const float4*)fc_w;
    float s = 0.0f;
#pragma unroll
    for (int q = 0; q < 16; ++q) {
        float4 v = hp[q];
        float4 w = wq[q];
        s += v.x * w.x + v.y * w.y + v.z * w.z + v.w * w.w;
    }
    s += fc_b[0];
    int b = idx >> 12;
    int n = idx & (NNP - 1);
#pragma unroll
    for (int t = 0; t < TS; ++t) out[(b * TS + t) * NNP + n] = s;
}

extern "C" void kernel_launch(void* const* d_in, const int* in_sizes, int n_in,
                              void* d_out, int out_size, void* d_ws, size_t ws_size,
                              hipStream_t stream) {
    const float* x      = (const float*)d_in[0];
    const float* conv_w = (const float*)d_in[1];
    const float* conv_b = (const float*)d_in[2];
    const float* fc_w   = (const float*)d_in[3];
    const float* fc_b   = (const float*)d_in[4];
    float* out = (float*)d_out;

    char* ws = (char*)d_ws;
    const size_t wp_bytes = (size_t)4 * KTOT * HID * sizeof(float);   // ~200 KB
    const size_t hc_bytes = (size_t)BB * NNP * HID * sizeof(float);   // 16.78 MB
    size_t off = (wp_bytes + 255) & ~(size_t)255;

    float* wp  = (float*)ws;
    float* h_a = (float*)(ws + off);
    float* h_b = (float*)(ws + off + hc_bytes);
    float* c   = (float*)(ws + off + 2 * hc_bytes);

    pack_w_kernel<<<(4 * KTOT * HID + 255) / 256, 256, 0, stream>>>(conv_w, wp);

    for (int t = 0; t < TS; ++t) {
        float* h_nxt = (t & 1) ? h_b : h_a;
        const float* h_prv = (t & 1) ? h_a : h_b;
        step_kernel<<<BB * (NNP / POS), 256, 0, stream>>>(
            x, wp, conv_b, h_prv, h_nxt, c, t);
    }
    // t=15 (odd) wrote h_b
    fc_kernel<<<BB * NNP / 256, 256, 0, stream>>>(h_b, fc_w, fc_b, out);
}

// Round 3
// 741.251 us; speedup vs baseline: 5.9804x; 2.3225x over previous
//
#include <hip/hip_runtime.h>
#include <hip/hip_cooperative_groups.h>

namespace cg = cooperative_groups;

typedef _Float16 f16;
typedef __attribute__((ext_vector_type(8))) _Float16 half8;
typedef __attribute__((ext_vector_type(4))) float floatx4;

#define BB   16
#define TSN  16
#define NNP  4096
#define HID  64
#define KPK  224      // 6 k-tiles of 32 (h taps) + 1 k-tile (x taps, 3 live lanes)
#define MBLK 128      // positions per block
#define HSTR 72       // hlds row stride in f16 (144 B, 16B-aligned for ds_read_b128)
#define NROW 130      // MBLK + 2 halo rows

// ---------------------------------------------------------------------------
// Pack conv_w (OIHW 256x65x3x3, only kw=1 column is live) into fp16
// wpack[oc][k], oc = g*64+hid, k = kt*32+c:
//   kt<6 : tap = kt>>1, j = (kt&1)*32+c  -> h-channel weight (ic = 1+j)
//   kt=6 : c<3 -> x-channel weight at tap c, else 0
// This matches the MFMA B-frag read: lane n=lane&15 (hid), k=(lane>>4)*8+i.
// ---------------------------------------------------------------------------
__global__ void pack_w_kernel(const float* __restrict__ conv_w, f16* __restrict__ wpack) {
    int idx = blockIdx.x * 256 + threadIdx.x;
    if (idx >= 4 * 64 * KPK) return;
    int k  = idx % KPK;
    int oc = idx / KPK;
    int kt = k >> 5, c = k & 31;
    float w = 0.0f;
    if (kt < 6) {
        int tap = kt >> 1;
        int j   = (kt & 1) * 32 + c;
        w = conv_w[((oc * 65 + 1 + j) * 3 + tap) * 3 + 1];
    } else if (c < 3) {
        w = conv_w[((oc * 65 + 0) * 3 + c) * 3 + 1];
    }
    wpack[oc * KPK + k] = (f16)w;
}

__device__ __forceinline__ float sigmoid_f(float v) { return 1.0f / (1.0f + __expf(-v)); }
__device__ __forceinline__ float tanh_f(float v) { float e = __expf(2.0f * v); return 1.0f - 2.0f / (e + 1.0f); }

// ---------------------------------------------------------------------------
// Persistent ConvLSTM kernel. Block = 256 thr (4 waves), owns batch b and
// positions [n0, n0+128). Wave w covers hid [w*16, w*16+16) x all 4 gates
// (4 MFMA N-subtiles, one per gate) -> epilogue is fully lane-local.
// coop=1: single cooperative launch, t0..t1, grid.sync between steps;
//         weights+c stay in registers, h exchanged via LDS + 2 boundary
//         rows per block in global.
// coop=0: one launch per step; c/h round-trip through global.
// MFMA layouts used (16x16x32 f16): A[m=lane&15][k=(lane>>4)*8+i],
// B[k=(lane>>4)*8+i][n=lane&15], C col=lane&15, row=(lane>>4)*4+reg.
// ---------------------------------------------------------------------------
__global__ __launch_bounds__(256, 2)
void lstm_kernel(const float* __restrict__ x, const f16* __restrict__ wpack,
                 const float* __restrict__ conv_b, f16* __restrict__ h_glob,
                 float* __restrict__ c_glob, int t0, int t1, int coop)
{
    __shared__ __align__(16) f16 hlds[NROW * HSTR];   // rr <-> position n0-1+rr
    __shared__ __align__(16) f16 xt[MBLK * 32];       // [r][kk]: x[n0+r+kk-1], kk<3

    const int blk  = blockIdx.x;
    const int b    = blk >> 5;
    const int n0   = (blk & 31) * MBLK;
    const int tid  = threadIdx.x;
    const int lane = tid & 63;
    const int wave = tid >> 6;
    const int m    = lane & 15;
    const int kg   = lane >> 4;
    const int hid_col = wave * 16 + m;

    // B fragments: 7 k-tiles x 4 gates, live in registers for all steps
    half8 bf[7][4];
#pragma unroll
    for (int kt = 0; kt < 7; ++kt)
#pragma unroll
        for (int g = 0; g < 4; ++g)
            bf[kt][g] = *(const half8*)(wpack + (g * 64 + hid_col) * KPK + kt * 32 + kg * 8);

    float bias[4];
#pragma unroll
    for (int g = 0; g < 4; ++g) bias[g] = conv_b[g * 64 + hid_col];

    // c in registers: [pass*16 + ms*4 + r] <-> pos = n0+pass*64+ms*16+kg*4+r, hid_col
    float creg[32];
#pragma unroll
    for (int i = 0; i < 32; ++i) creg[i] = 0.0f;
    if (!coop && t0 > 0) {
#pragma unroll
        for (int pass = 0; pass < 2; ++pass)
#pragma unroll
            for (int ms = 0; ms < 4; ++ms)
#pragma unroll
                for (int r = 0; r < 4; ++r) {
                    int pos = n0 + pass * 64 + ms * 16 + kg * 4 + r;
                    creg[pass * 16 + ms * 4 + r] = c_glob[(size_t)(b * NNP + pos) * HID + hid_col];
                }
    }

    // zero xt (cols >= 3 must stay zero); zero hlds when starting at t=0
    for (int i = tid; i < MBLK * 32; i += 256) xt[i] = (f16)0;
    if (t0 == 0)
        for (int i = tid; i < NROW * HSTR; i += 256) hlds[i] = (f16)0;
    __syncthreads();

    f16 hn63 = (f16)0;   // deferred hlds row-64 write (pass0's last row)

    for (int t = t0; t < t1; ++t) {
        const bool fullw = (!coop) || (t == TSN - 1);

        // ---- stage ----
        if (t > 0) {
            if (coop) {
                // only the 2 halo rows come from global (neighbors' boundary writes)
                if (tid < 64) {
                    int rr = (tid < 32) ? 0 : (NROW - 1);
                    int q  = tid & 31;
                    int n  = n0 - 1 + rr;
                    unsigned int v = 0u;
                    if (n >= 0 && n < NNP)
                        v = ((const unsigned int*)(h_glob + (size_t)(b * NNP + n) * HID))[q];
                    ((unsigned int*)(hlds + rr * HSTR))[q] = v;
                }
            } else {
                for (int idx = tid; idx < NROW * 8; idx += 256) {
                    int rr = idx >> 3, q = idx & 7;
                    int n  = n0 - 1 + rr;
                    half8 v = {};
                    if (n >= 0 && n < NNP)
                        v = *(const half8*)(h_glob + (size_t)(b * NNP + n) * HID + q * 8);
                    *(half8*)(hlds + rr * HSTR + q * 8) = v;
                }
            }
        }
        {   // x window for this step
            const float* xb = x + ((size_t)b * TSN + t) * NNP;
            for (int r = tid; r < MBLK; r += 256) {
                int p = n0 + r;
                xt[r * 32 + 0] = (f16)((p >= 1) ? xb[p - 1] : 0.0f);
                xt[r * 32 + 1] = (f16)xb[p];
                xt[r * 32 + 2] = (f16)((p + 1 < NNP) ? xb[p + 1] : 0.0f);
            }
        }
        __syncthreads();

#pragma unroll
        for (int pass = 0; pass < 2; ++pass) {
            const int rbase = pass * 64;
            floatx4 acc[4][4];
#pragma unroll
            for (int ms = 0; ms < 4; ++ms)
#pragma unroll
                for (int g = 0; g < 4; ++g) acc[ms][g] = (floatx4){0.f, 0.f, 0.f, 0.f};

#pragma unroll
            for (int ms = 0; ms < 4; ++ms) {
                const int arow = rbase + ms * 16 + m;
#pragma unroll
                for (int kt = 0; kt < 6; ++kt) {
                    const int tap = kt >> 1;
                    half8 a = *(const half8*)(hlds + (arow + tap) * HSTR + (kt & 1) * 32 + kg * 8);
#pragma unroll
                    for (int g = 0; g < 4; ++g)
                        acc[ms][g] = __builtin_amdgcn_mfma_f32_16x16x32_f16(a, bf[kt][g], acc[ms][g], 0, 0, 0);
                }
                {
                    half8 a = *(const half8*)(xt + (rbase + ms * 16 + m) * 32 + kg * 8);
#pragma unroll
                    for (int g = 0; g < 4; ++g)
                        acc[ms][g] = __builtin_amdgcn_mfma_f32_16x16x32_f16(a, bf[6][g], acc[ms][g], 0, 0, 0);
                }
            }

            // all waves must finish reading h(t-1) rows of this pass before
            // any wave overwrites them with h(t)
            __syncthreads();

            // ---- epilogue (lane-local: this lane owns (pos rows, hid_col) for all gates)
#pragma unroll
            for (int ms = 0; ms < 4; ++ms) {
#pragma unroll
                for (int r = 0; r < 4; ++r) {
                    int ridx = pass * 16 + ms * 4 + r;
                    float gi = acc[ms][0][r] + bias[0];
                    float gf = acc[ms][1][r] + bias[1];
                    float go = acc[ms][2][r] + bias[2];
                    float gg = acc[ms][3][r] + bias[3];
                    float c_old = creg[ridx];
                    float cn = sigmoid_f(gf) * c_old + sigmoid_f(gi) * tanh_f(gg);
                    float hn = sigmoid_f(go) * tanh_f(cn);
                    creg[ridx] = cn;
                    f16 hh = (f16)hn;
                    int rit = ms * 16 + kg * 4 + r;   // row within this 64-pass
                    int pos = n0 + rbase + rit;
                    if (coop) {
                        if (pass == 0 && rit == 63) hn63 = hh;  // rr64 still read by pass1
                        else hlds[(rbase + rit + 1) * HSTR + hid_col] = hh;
                        if ((pass == 0 && rit == 0) || (pass == 1 && rit == 63) || fullw)
                            h_glob[(size_t)(b * NNP + pos) * HID + hid_col] = hh;
                    } else {
                        h_glob[(size_t)(b * NNP + pos) * HID + hid_col] = hh;
                    }
                }
            }
        }

        if (coop) {
            // deferred row-64 write: pass1's post-MFMA barrier guarantees no reader left
            if (kg == 3) hlds[64 * HSTR + hid_col] = hn63;
            if (t + 1 < t1) cg::this_grid().sync();
        }
    }

    if (!coop) {
#pragma unroll
        for (int pass = 0; pass < 2; ++pass)
#pragma unroll
            for (int ms = 0; ms < 4; ++ms)
#pragma unroll
                for (int r = 0; r < 4; ++r) {
                    int pos = n0 + pass * 64 + ms * 16 + kg * 4 + r;
                    c_glob[(size_t)(b * NNP + pos) * HID + hid_col] = creg[pass * 16 + ms * 4 + r];
                }
    }
}

// ---------------------------------------------------------------------------
// fc: out[b,t,n] = sum_hid h[b][n][hid]*fc_w[hid] + fc_b, broadcast over t
// ---------------------------------------------------------------------------
__global__ void fc_kernel(const f16* __restrict__ h, const float* __restrict__ fc_w,
                          const float* __restrict__ fc_b, float* __restrict__ out) {
    int idx = blockIdx.x * 256 + threadIdx.x;      // b*NNP + n
    const half8* hp = (const half8*)(h + (size_t)idx * HID);
    float s = 0.0f;
#pragma unroll
    for (int q = 0; q < 8; ++q) {
        half8 v = hp[q];
#pragma unroll
        for (int e = 0; e < 8; ++e) s += (float)v[e] * fc_w[q * 8 + e];
    }
    s += fc_b[0];
    int b = idx >> 12, n = idx & (NNP - 1);
#pragma unroll
    for (int t = 0; t < TSN; ++t) out[((size_t)b * TSN + t) * NNP + n] = s;
}

extern "C" void kernel_launch(void* const* d_in, const int* in_sizes, int n_in,
                              void* d_out, int out_size, void* d_ws, size_t ws_size,
                              hipStream_t stream) {
    const float* x      = (const float*)d_in[0];
    const float* conv_w = (const float*)d_in[1];
    const float* conv_b = (const float*)d_in[2];
    const float* fc_w   = (const float*)d_in[3];
    const float* fc_b   = (const float*)d_in[4];
    float* out = (float*)d_out;

    char* ws = (char*)d_ws;
    f16*   wpack  = (f16*)ws;                                   // 4*64*224*2 = 112 KiB
    f16*   h_glob = (f16*)(ws + 131072);                        // 8.39 MB
    float* c_glob = (float*)(ws + 131072 + (size_t)BB * NNP * HID * 2);  // 16.78 MB (fallback only)

    pack_w_kernel<<<(4 * 64 * KPK + 255) / 256, 256, 0, stream>>>(conv_w, wpack);

    int dev = 0;
    hipGetDevice(&dev);
    int coopAttr = 0, smCount = 0, nb = 0;
    hipDeviceGetAttribute(&coopAttr, hipDeviceAttributeCooperativeLaunch, dev);
    hipDeviceGetAttribute(&smCount, hipDeviceAttributeMultiprocessorCount, dev);
    hipOccupancyMaxActiveBlocksPerMultiprocessor(&nb, (const void*)lstm_kernel, 256, 0);

    bool coop = (coopAttr != 0) && ((long)nb * smCount >= 512);
    if (coop) {
        int t0 = 0, t1 = TSN, cf = 1;
        void* args[] = {(void*)&x, (void*)&wpack, (void*)&conv_b,
                        (void*)&h_glob, (void*)&c_glob, (void*)&t0, (void*)&t1, (void*)&cf};
        hipError_t e = hipLaunchCooperativeKernel((const void*)lstm_kernel,
                                                  dim3(512), dim3(256), args, 0, stream);
        if (e != hipSuccess) coop = false;
    }
    if (!coop) {
        for (int t = 0; t < TSN; ++t)
            lstm_kernel<<<512, 256, 0, stream>>>(x, wpack, conv_b, h_glob, c_glob, t, t + 1, 0);
    }

    fc_kernel<<<BB * NNP / 256, 256, 0, stream>>>(h_glob, fc_w, fc_b, out);
}

// Round 4
// 576.683 us; speedup vs baseline: 7.6871x; 1.2854x over previous
//
#include <hip/hip_runtime.h>
#include <hip/hip_cooperative_groups.h>

namespace cg = cooperative_groups;

typedef _Float16 f16;
typedef __attribute__((ext_vector_type(8))) _Float16 half8;
typedef __attribute__((ext_vector_type(4))) float floatx4;

#define BB   16
#define TSN  16
#define NNP  4096
#define HID  64
#define KPK  224      // 6 k-tiles of 32 (h taps) + 1 k-tile (x taps, 3 live)
#define MBLK 128      // positions per block
#define HSTR 72       // hlds row stride in f16 (144 B, 16B-aligned)
#define NROW 130      // MBLK + 2 halo rows

// ---------------------------------------------------------------------------
// Pack conv_w (OIHW 256x65x3x3, only kw=1 live) -> f16 wpack[oc][k]:
//   k = kt*32+c;  kt<6: tap=kt>>1, ch j=(kt&1)*32+c;  kt=6: c<3 -> x tap c.
// ---------------------------------------------------------------------------
__global__ void pack_w_kernel(const float* __restrict__ conv_w, f16* __restrict__ wpack) {
    int idx = blockIdx.x * 256 + threadIdx.x;
    if (idx >= 4 * 64 * KPK) return;
    int k  = idx % KPK;
    int oc = idx / KPK;
    int kt = k >> 5, c = k & 31;
    float w = 0.0f;
    if (kt < 6) {
        int tap = kt >> 1;
        int j   = (kt & 1) * 32 + c;
        w = conv_w[((oc * 65 + 1 + j) * 3 + tap) * 3 + 1];
    } else if (c < 3) {
        w = conv_w[((oc * 65 + 0) * 3 + c) * 3 + 1];
    }
    wpack[oc * KPK + k] = (f16)w;
}

__device__ __forceinline__ float sigmoid_f(float v) { return 1.0f / (1.0f + __expf(-v)); }
__device__ __forceinline__ float tanh_f(float v) { float e = __expf(2.0f * v); return 1.0f - 2.0f / (e + 1.0f); }

// ---------------------------------------------------------------------------
// Persistent ConvLSTM. Block = 256 thr (4 waves), batch b, positions
// [n0, n0+128). Wave w: hid [w*16,w*16+16) x 4 gates (lane-local epilogue).
// Double-buffered hlds: read buf p=t&1, write buf p^1 -> no intra-step
// post-MFMA barrier, per-ms epilogue keeps acc live-range at 16 VGPRs.
// coop=1: one launch, grid.sync per step, c in regs, only 2 boundary rows
//         per block via global. coop=0: per-step launch, h ping-pong via
//         global (h_in/h_out), c via c_glob.
// ---------------------------------------------------------------------------
__global__ __launch_bounds__(256, 2)
void lstm_kernel(const float* __restrict__ x, const f16* __restrict__ wpack,
                 const float* __restrict__ conv_b,
                 const f16* __restrict__ h_in, f16* __restrict__ h_out,
                 float* __restrict__ c_glob, int t0, int t1, int coop)
{
    __shared__ __align__(16) f16 hlds[2][NROW * HSTR];
    __shared__ __align__(16) f16 xt[MBLK * 32];

    const int blk  = blockIdx.x;
    const int b    = blk >> 5;
    const int n0   = (blk & 31) * MBLK;
    const int tid  = threadIdx.x;
    const int lane = tid & 63;
    const int wave = tid >> 6;
    const int m    = lane & 15;
    const int kg   = lane >> 4;
    const int hid_col = wave * 16 + m;

    // B fragments: 7 k-tiles x 4 gates, resident in registers for all steps
    half8 bf[7][4];
#pragma unroll
    for (int kt = 0; kt < 7; ++kt)
#pragma unroll
        for (int g = 0; g < 4; ++g)
            bf[kt][g] = *(const half8*)(wpack + (g * 64 + hid_col) * KPK + kt * 32 + kg * 8);

    float bias[4];
#pragma unroll
    for (int g = 0; g < 4; ++g) bias[g] = conv_b[g * 64 + hid_col];

    // c in registers: creg[pass*16+ms*4+r] <-> pos n0+pass*64+ms*16+kg*4+r
    float creg[32];
#pragma unroll
    for (int i = 0; i < 32; ++i) creg[i] = 0.0f;
    if (!coop && t0 > 0) {
#pragma unroll
        for (int pass = 0; pass < 2; ++pass)
#pragma unroll
            for (int ms = 0; ms < 4; ++ms)
#pragma unroll
                for (int r = 0; r < 4; ++r) {
                    int pos = n0 + pass * 64 + ms * 16 + kg * 4 + r;
                    creg[pass * 16 + ms * 4 + r] = c_glob[(size_t)(b * NNP + pos) * HID + hid_col];
                }
    }

    // zero xt (cols >=3 stay zero forever); zero read-buffer 0 at t=0
    for (int i = tid; i < MBLK * 32; i += 256) xt[i] = (f16)0;
    if (t0 == 0)
        for (int i = tid; i < NROW * HSTR; i += 256) hlds[0][i] = (f16)0;
    __syncthreads();

    for (int t = t0; t < t1; ++t) {
        const int p = coop ? (t & 1) : 0;
        const f16* hrd = hlds[p];
        f16*       hwr = hlds[p ^ 1];

        // ---- stage ----
        if (t > 0) {
            if (coop) {
                // halo rows 0 and 129 come from neighbors' boundary writes
                if (tid < 64) {
                    int rr = (tid < 32) ? 0 : (NROW - 1);
                    int q  = tid & 31;
                    int n  = n0 - 1 + rr;
                    unsigned int v = 0u;
                    if (n >= 0 && n < NNP)
                        v = ((const unsigned int*)(h_in + (size_t)(b * NNP + n) * HID))[q];
                    ((unsigned int*)((f16*)hrd + rr * HSTR))[q] = v;
                }
            } else {
                for (int idx = tid; idx < NROW * 8; idx += 256) {
                    int rr = idx >> 3, q = idx & 7;
                    int n  = n0 - 1 + rr;
                    half8 v = {};
                    if (n >= 0 && n < NNP)
                        v = *(const half8*)(h_in + (size_t)(b * NNP + n) * HID + q * 8);
                    *(half8*)((f16*)hrd + rr * HSTR + q * 8) = v;
                }
            }
        }
        {   // x window for this step
            const float* xb = x + ((size_t)b * TSN + t) * NNP;
            for (int r = tid; r < MBLK; r += 256) {
                int pp = n0 + r;
                xt[r * 32 + 0] = (f16)((pp >= 1) ? xb[pp - 1] : 0.0f);
                xt[r * 32 + 1] = (f16)xb[pp];
                xt[r * 32 + 2] = (f16)((pp + 1 < NNP) ? xb[pp + 1] : 0.0f);
            }
        }
        __syncthreads();

        const bool fullw = (!coop) || (t == TSN - 1);

#pragma unroll
        for (int pass = 0; pass < 2; ++pass) {
            const int rbase = pass * 64;
#pragma unroll
            for (int ms = 0; ms < 4; ++ms) {
                const int arow = rbase + ms * 16 + m;
                const f16* abase = hrd + arow * HSTR + kg * 8;

                floatx4 acc[4];
#pragma unroll
                for (int g = 0; g < 4; ++g) acc[g] = (floatx4){0.f, 0.f, 0.f, 0.f};

#pragma unroll
                for (int kt = 0; kt < 6; ++kt) {
                    half8 a = *(const half8*)(abase + (kt >> 1) * HSTR + (kt & 1) * 32);
#pragma unroll
                    for (int g = 0; g < 4; ++g)
                        acc[g] = __builtin_amdgcn_mfma_f32_16x16x32_f16(a, bf[kt][g], acc[g], 0, 0, 0);
                }
                {
                    half8 a = *(const half8*)(xt + arow * 32 + kg * 8);
#pragma unroll
                    for (int g = 0; g < 4; ++g)
                        acc[g] = __builtin_amdgcn_mfma_f32_16x16x32_f16(a, bf[6][g], acc[g], 0, 0, 0);
                }

                // per-ms epilogue: lane owns (4 rows, hid_col, all gates)
#pragma unroll
                for (int r = 0; r < 4; ++r) {
                    int ridx = pass * 16 + ms * 4 + r;
                    float gi = acc[0][r] + bias[0];
                    float gf = acc[1][r] + bias[1];
                    float go = acc[2][r] + bias[2];
                    float gg = acc[3][r] + bias[3];
                    float cn = sigmoid_f(gf) * creg[ridx] + sigmoid_f(gi) * tanh_f(gg);
                    float hn = sigmoid_f(go) * tanh_f(cn);
                    creg[ridx] = cn;
                    f16 hh = (f16)hn;
                    int rit = ms * 16 + kg * 4 + r;       // row within this pass
                    int pos = n0 + rbase + rit;
                    if (coop) {
                        hwr[(rbase + rit + 1) * HSTR + hid_col] = hh;
                        if (fullw || (pass == 0 && rit == 0) || (pass == 1 && rit == 63))
                            h_out[(size_t)(b * NNP + pos) * HID + hid_col] = hh;
                    } else {
                        h_out[(size_t)(b * NNP + pos) * HID + hid_col] = hh;
                    }
                }
            }
        }

        if (coop && t + 1 < t1) cg::this_grid().sync();
    }

    if (!coop) {
#pragma unroll
        for (int pass = 0; pass < 2; ++pass)
#pragma unroll
            for (int ms = 0; ms < 4; ++ms)
#pragma unroll
                for (int r = 0; r < 4; ++r) {
                    int pos = n0 + pass * 64 + ms * 16 + kg * 4 + r;
                    c_glob[(size_t)(b * NNP + pos) * HID + hid_col] = creg[pass * 16 + ms * 4 + r];
                }
    }
}

// ---------------------------------------------------------------------------
// fc: out[b,t,n] = sum_hid h[b][n][hid]*fc_w[hid] + fc_b, broadcast over t
// ---------------------------------------------------------------------------
__global__ void fc_kernel(const f16* __restrict__ h, const float* __restrict__ fc_w,
                          const float* __restrict__ fc_b, float* __restrict__ out) {
    int idx = blockIdx.x * 256 + threadIdx.x;      // b*NNP + n
    const half8* hp = (const half8*)(h + (size_t)idx * HID);
    float s = 0.0f;
#pragma unroll
    for (int q = 0; q < 8; ++q) {
        half8 v = hp[q];
#pragma unroll
        for (int e = 0; e < 8; ++e) s += (float)v[e] * fc_w[q * 8 + e];
    }
    s += fc_b[0];
    int b = idx >> 12, n = idx & (NNP - 1);
#pragma unroll
    for (int t = 0; t < TSN; ++t) out[((size_t)b * TSN + t) * NNP + n] = s;
}

extern "C" void kernel_launch(void* const* d_in, const int* in_sizes, int n_in,
                              void* d_out, int out_size, void* d_ws, size_t ws_size,
                              hipStream_t stream) {
    const float* x      = (const float*)d_in[0];
    const float* conv_w = (const float*)d_in[1];
    const float* conv_b = (const float*)d_in[2];
    const float* fc_w   = (const float*)d_in[3];
    const float* fc_b   = (const float*)d_in[4];
    float* out = (float*)d_out;

    char* ws = (char*)d_ws;
    const size_t hbytes = (size_t)BB * NNP * HID * sizeof(f16);     // 8.39 MB
    f16*   wpack  = (f16*)ws;                                       // 112 KiB
    f16*   h_a    = (f16*)(ws + 131072);
    f16*   h_b    = (f16*)(ws + 131072 + hbytes);
    float* c_glob = (float*)(ws + 131072 + 2 * hbytes);             // fallback only

    pack_w_kernel<<<(4 * 64 * KPK + 255) / 256, 256, 0, stream>>>(conv_w, wpack);

    int dev = 0;
    hipGetDevice(&dev);
    int coopAttr = 0, smCount = 0, nb = 0;
    hipDeviceGetAttribute(&coopAttr, hipDeviceAttributeCooperativeLaunch, dev);
    hipDeviceGetAttribute(&smCount, hipDeviceAttributeMultiprocessorCount, dev);
    hipOccupancyMaxActiveBlocksPerMultiprocessor(&nb, (const void*)lstm_kernel, 256, 0);

    bool coop = (coopAttr != 0) && ((long)nb * smCount >= 512);
    if (coop) {
        int t0 = 0, t1 = TSN, cf = 1;
        const f16* hi = h_a; f16* ho = h_a;
        void* args[] = {(void*)&x, (void*)&wpack, (void*)&conv_b,
                        (void*)&hi, (void*)&ho, (void*)&c_glob,
                        (void*)&t0, (void*)&t1, (void*)&cf};
        hipError_t e = hipLaunchCooperativeKernel((const void*)lstm_kernel,
                                                  dim3(512), dim3(256), args, 0, stream);
        if (e != hipSuccess) coop = false;
    }
    if (!coop) {
        for (int t = 0; t < TSN; ++t) {
            const f16* hi = (t & 1) ? h_b : h_a;   // = h_out of step t-1
            f16*       ho = (t & 1) ? h_a : h_b;
            // note: t=0 writes h_b, t=15 writes ... (15&1)=1 -> h_a. fc reads h_a.
            lstm_kernel<<<512, 256, 0, stream>>>(x, wpack, conv_b, hi, ho, c_glob, t, t + 1, 0);
        }
    }

    fc_kernel<<<BB * NNP / 256, 256, 0, stream>>>(h_a, fc_w, fc_b, out);
}